// Round 9
// baseline (66.552 us; speedup 1.0000x reference)
//
#include <hip/hip_runtime.h>
#include <math.h>

namespace {

constexpr int L      = 3750;
constexpr int NPAIR  = L / 2;     // 1875 float2 per row
constexpr int BLK    = 128;       // 2 waves per row
constexpr int CH     = 30;        // chunk per thread (stride 30 floats: 2-way = free)
constexpr int NCHUNK = L / CH;    // 125 active chunk threads
constexpr float EPS  = 1e-5f;

__device__ __forceinline__ float frcp(float x)  { return __builtin_amdgcn_rcpf(x); }
__device__ __forceinline__ float fsqrt(float x) { return __builtin_amdgcn_sqrtf(x); }

__global__ __launch_bounds__(BLK, 5)
void preproc_kernel(const float* __restrict__ in, float* __restrict__ out) {
    // ONE row-sized LDS array, reused: staging -> y-prefix -> u^2-prefix -> result
    __shared__ __align__(16) float sp[L + 2];
    __shared__ float sred[4];     // [0:2) wave sums, [2:4) wave sumsq

    const int tid  = threadIdx.x;
    const int lane = tid & 63;
    const int wave = tid >> 6;
    const size_t rowoff = (size_t)blockIdx.x * (size_t)L;
    const float* rin  = in  + rowoff;
    float*       rout = out + rowoff;

    const bool active = (tid < NCHUNK);
    const int  base   = tid * CH;             // even -> float2-aligned chunk

    // ---- 1. coalesced load of the row into sp[0..L) ----
    {
        const float2* rin2 = reinterpret_cast<const float2*>(rin);
        float2* sp2 = reinterpret_cast<float2*>(sp);
        for (int i = tid; i < NPAIR; i += BLK) sp2[i] = rin2[i];
    }
    __syncthreads();                          // B1

    // ---- 2. chunk -> registers (15 x b64); block reduce sum/sumsq ----
    float y[CH];
    float cy = 0.f, cy2 = 0.f;
    if (active) {
        const float2* s2 = reinterpret_cast<const float2*>(sp) + 15 * tid;
        #pragma unroll
        for (int h = 0; h < 15; ++h) {
            const float2 v = s2[h];
            y[2*h]   = v.x;
            y[2*h+1] = v.y;
            cy  += v.x + v.y;
            cy2  = fmaf(v.x, v.x, cy2);
            cy2  = fmaf(v.y, v.y, cy2);
        }
    } else {
        #pragma unroll
        for (int j = 0; j < CH; ++j) y[j] = 0.f;
    }
    float iy = cy;
    #pragma unroll
    for (int d = 1; d < 64; d <<= 1) {
        const float u = __shfl_up(iy, (unsigned)d, 64);
        if (lane >= d) iy += u;
    }
    float t2 = cy2;
    #pragma unroll
    for (int d = 1; d < 64; d <<= 1) t2 += __shfl_xor(t2, d, 64);
    if (lane == 63) { sred[wave] = iy; sred[2 + wave] = t2; }
    __syncthreads();                          // B2: sred ready, sp reads done
    const float woff  = (wave == 1) ? sred[0] : 0.f;
    const float totY  = sred[0] + sred[1];
    const float totY2 = sred[2] + sred[3];
    const float mean  = totY * (1.f / (float)L);
    const float var   = (totY2 - totY * mean) * (1.f / (float)(L - 1));
    const float s     = fsqrt(var) + EPS;     // std + eps
    const float epsS  = EPS * s;              // r = u / (sqrt(MV(u^2)) + eps*s)

    // ---- 3. exclusive raw-y prefix -> sp (15 x b64) ----
    if (active) {
        float run = woff + iy - cy;           // exclusive prefix at chunk start
        float2* w2 = reinterpret_cast<float2*>(sp) + 15 * tid;
        #pragma unroll
        for (int h = 0; h < 15; ++h) {
            float2 w;
            w.x = run; run += y[2*h];
            w.y = run; run += y[2*h+1];
            w2[h] = w;
        }
        if (tid == NCHUNK - 1) sp[L] = run;
    }
    __syncthreads();                          // B3: y-prefix ready

    // ---- 4. pass B: u = y - MA_sum(y)/251 (z-norm cancels in interior) ----
    const float inv251 = 1.f / 251.f;
    float cu = 0.f;
    if (active) {
        if (tid >= 5 && tid <= 119) {         // untruncated windows for all 30 elems
            const float2* hi2 = reinterpret_cast<const float2*>(sp) + 15 * tid + 63;
            const float*  pl  = sp + base - 125;
            #pragma unroll
            for (int h = 0; h < 15; ++h) {
                const float2 hi = hi2[h];     // P[i0+126], P[i0+127] (aligned b64)
                const float lo0 = pl[2*h];    // P[i0-125]
                const float lo1 = pl[2*h+1];  // P[i0-124]  (read2-mergeable)
                float u0 = fmaf(hi.x - lo0, -inv251, y[2*h]);
                float u1 = fmaf(hi.y - lo1, -inv251, y[2*h+1]);
                y[2*h]   = u0;
                y[2*h+1] = u1;
                cu = fmaf(u0, u0, cu);
                cu = fmaf(u1, u1, cu);
            }
        } else {                              // clamped: mean correction
            #pragma unroll
            for (int j = 0; j < CH; ++j) {
                const int i  = base + j;
                const int lo = (i > 125) ? i - 125 : 0;
                const int hi = (i + 126 < L) ? i + 126 : L;
                const float sumY = sp[hi] - sp[lo];
                const float cnt  = (float)(hi - lo);
                float u = y[j] - mean * (1.f - cnt * inv251);
                u = fmaf(sumY, -inv251, u);
                y[j] = u;
                cu   = fmaf(u, u, cu);
            }
        }
    }
    float iu = cu;
    #pragma unroll
    for (int d = 1; d < 64; d <<= 1) {
        const float u = __shfl_up(iu, (unsigned)d, 64);
        if (lane >= d) iu += u;
    }
    if (lane == 63) sred[wave] = iu;          // safe: sred reads ended before B3
    __syncthreads();                          // B4: window reads done, sred(B) ready
    const float woff2 = (wave == 1) ? sred[0] : 0.f;

    // ---- 5. exclusive u^2-prefix -> sp (15 x b64) ----
    if (active) {
        float run = woff2 + iu - cu;
        float2* w2 = reinterpret_cast<float2*>(sp) + 15 * tid;
        #pragma unroll
        for (int h = 0; h < 15; ++h) {
            float2 w;
            w.x = run; run = fmaf(y[2*h],   y[2*h],   run);
            w.y = run; run = fmaf(y[2*h+1], y[2*h+1], run);
            w2[h] = w;
        }
        if (tid == NCHUNK - 1) sp[L] = run;
    }
    __syncthreads();                          // B5: u^2-prefix ready

    // ---- 6. epilogue: r = u / (sqrt(MV)+eps*s), in registers ----
    const float inv501 = 1.f / 501.f;
    if (active) {
        if (tid >= 9 && tid <= 115) {         // untruncated MV windows
            const float2* lo2 = reinterpret_cast<const float2*>(sp) + 15 * tid - 125;
            const float*  ph  = sp + base + 251;
            #pragma unroll
            for (int h = 0; h < 15; ++h) {
                const float2 lo = lo2[h];     // P[i0-250], P[i0-249] (aligned b64)
                const float hi0 = ph[2*h];    // P[i0+251]
                const float hi1 = ph[2*h+1];  // P[i0+252]  (read2-mergeable)
                float W0 = (hi0 - lo.x) * inv501;
                float W1 = (hi1 - lo.y) * inv501;
                W0 = fmaxf(W0, 0.f);
                W1 = fmaxf(W1, 0.f);
                y[2*h]   = y[2*h]   * frcp(fsqrt(W0) + epsS);
                y[2*h+1] = y[2*h+1] * frcp(fsqrt(W1) + epsS);
            }
        } else {                              // clamped
            #pragma unroll
            for (int j = 0; j < CH; ++j) {
                const int i  = base + j;
                const int lo = (i > 250) ? i - 250 : 0;
                const int hi = (i + 251 < L) ? i + 251 : L;
                float W = (sp[hi] - sp[lo]) * inv501;
                W = fmaxf(W, 0.f);
                y[j] = y[j] * frcp(fsqrt(W) + epsS);
            }
        }
    }
    __syncthreads();                          // B6: all prefix reads done

    // ---- 7. bounce r through sp (15 x b64, chunk layout == linear) ----
    if (active) {
        float2* w2 = reinterpret_cast<float2*>(sp) + 15 * tid;
        #pragma unroll
        for (int h = 0; h < 15; ++h) {
            float2 v;
            v.x = y[2*h];
            v.y = y[2*h+1];
            w2[h] = v;
        }
    }
    __syncthreads();                          // B7: result staged

    // ---- 8. coalesced store ----
    {
        const float2* sp2 = reinterpret_cast<const float2*>(sp);
        float2* rout2 = reinterpret_cast<float2*>(rout);
        for (int i = tid; i < NPAIR; i += BLK) rout2[i] = sp2[i];
    }
}

}  // namespace

extern "C" void kernel_launch(void* const* d_in, const int* in_sizes, int n_in,
                              void* d_out, int out_size, void* d_ws, size_t ws_size,
                              hipStream_t stream) {
    const float* x = (const float*)d_in[0];
    float* out = (float*)d_out;
    const int rows = in_sizes[0] / L;   // 8192
    preproc_kernel<<<rows, BLK, 0, stream>>>(x, out);
}

// Round 10
// 44.605 us; speedup vs baseline: 1.4920x; 1.4920x over previous
//
#include <hip/hip_runtime.h>
#include <math.h>

namespace {

constexpr int L      = 3750;
constexpr int NPAIR  = L / 2;     // 1875 float2 per row
constexpr int BLK    = 256;
constexpr int CH     = 15;        // chunk per thread (odd stride => conflict-free)
constexpr int NCHUNK = L / CH;    // 250 active chunk threads
constexpr int NFULL  = NPAIR / BLK;          // 7 full I/O rounds
constexpr int NTAIL  = NPAIR - NFULL * BLK;  // 83
constexpr float EPS  = 1e-5f;

__device__ __forceinline__ float frcp(float x)  { return __builtin_amdgcn_rcpf(x); }
__device__ __forceinline__ float fsqrt(float x) { return __builtin_amdgcn_sqrtf(x); }
__device__ __forceinline__ float frsq(float x)  { return __builtin_amdgcn_rsqf(x); }

__global__ __launch_bounds__(BLK, 8)
void preproc_kernel(const float* __restrict__ in, float* __restrict__ out) {
    // ONE row-sized LDS array, reused: staging -> y-prefix -> u^2-prefix -> result
    __shared__ __align__(16) float sp[L + 2];
    __shared__ float sred[8];     // wave partials: [0:4) sum, [4:8) sumsq

    const int tid  = threadIdx.x;
    const int lane = tid & 63;
    const int wave = tid >> 6;
    const size_t rowoff = (size_t)blockIdx.x * (size_t)L;
    const float* rin  = in  + rowoff;
    float*       rout = out + rowoff;

    const bool active = (tid < NCHUNK);
    const int  base   = tid * CH;
    const bool tl     = (tid < NTAIL);

    // ---- 1. coalesced load (batched: all loads in flight, then LDS writes) ----
    {
        const float2* rin2 = reinterpret_cast<const float2*>(rin);
        float2 v[NFULL + 1];
        #pragma unroll
        for (int k = 0; k < NFULL; ++k) v[k] = rin2[k * BLK + tid];
        if (tl) v[NFULL] = rin2[NFULL * BLK + tid];
        float2* sp2 = reinterpret_cast<float2*>(sp);
        #pragma unroll
        for (int k = 0; k < NFULL; ++k) sp2[k * BLK + tid] = v[k];
        if (tl) sp2[NFULL * BLK + tid] = v[NFULL];
    }
    __syncthreads();                          // B1

    // ---- 2. chunk -> registers; block reduce (sum via scan, sumsq via xor) ----
    float y[CH];
    float cy = 0.f, cy2 = 0.f;
    if (active) {
        #pragma unroll
        for (int j = 0; j < CH; ++j) {
            const float v = sp[base + j];
            y[j] = v;
            cy  += v;
            cy2  = fmaf(v, v, cy2);
        }
    } else {
        #pragma unroll
        for (int j = 0; j < CH; ++j) y[j] = 0.f;
    }
    float iy = cy;
    #pragma unroll
    for (int d = 1; d < 64; d <<= 1) {
        const float u = __shfl_up(iy, (unsigned)d, 64);
        if (lane >= d) iy += u;
    }
    float t2 = cy2;
    #pragma unroll
    for (int d = 1; d < 64; d <<= 1) t2 += __shfl_xor(t2, d, 64);
    if (lane == 63) { sred[wave] = iy; sred[4 + wave] = t2; }
    __syncthreads();                          // B2: sred ready, sp reads done
    float woff = 0.f;
    #pragma unroll
    for (int w = 0; w < 4; ++w) if (w < wave) woff += sred[w];
    const float totY  = sred[0] + sred[1] + sred[2] + sred[3];
    const float totY2 = sred[4] + sred[5] + sred[6] + sred[7];
    const float mean  = totY * (1.f / (float)L);
    const float var   = (totY2 - totY * mean) * (1.f / (float)(L - 1));
    const float s     = fsqrt(var) + EPS;     // std + eps
    const float epsS  = EPS * s;              // r = u / (sqrt(MV(u^2)) + eps*s)

    // ---- 3. exclusive raw-y prefix -> sp ----
    {
        float run = woff + iy - cy;           // exclusive prefix at chunk start
        if (active) {
            #pragma unroll
            for (int j = 0; j < CH; ++j) { sp[base + j] = run; run += y[j]; }
            if (tid == NCHUNK - 1) sp[L] = run;
        }
    }
    __syncthreads();                          // B3: y-prefix ready

    // ---- 4. pass B: u = y - MA_sum(y)/251 (z-norm cancels in interior) ----
    const float inv251 = 1.f / 251.f;
    float cu = 0.f;
    if (active) {
        if (tid >= 9 && tid <= 240) {         // untruncated windows, no mean
            #pragma unroll
            for (int j = 0; j < CH; ++j) {
                const int i = base + j;
                const float sumY = sp[i + 126] - sp[i - 125];
                const float u = fmaf(sumY, -inv251, y[j]);
                y[j] = u;
                cu   = fmaf(u, u, cu);
            }
        } else {                              // clamped: mean correction
            #pragma unroll
            for (int j = 0; j < CH; ++j) {
                const int i  = base + j;
                const int lo = (i > 125) ? i - 125 : 0;
                const int hi = (i + 126 < L) ? i + 126 : L;
                const float sumY = sp[hi] - sp[lo];
                const float cnt  = (float)(hi - lo);
                // u = y - m*(1 - cnt/251) - sumY/251
                float u = y[j] - mean * (1.f - cnt * inv251);
                u = fmaf(sumY, -inv251, u);
                y[j] = u;
                cu   = fmaf(u, u, cu);
            }
        }
    }
    float iu = cu;
    #pragma unroll
    for (int d = 1; d < 64; d <<= 1) {
        const float u = __shfl_up(iu, (unsigned)d, 64);
        if (lane >= d) iu += u;
    }
    if (lane == 63) sred[wave] = iu;          // safe: sred(A) last read before B3
    __syncthreads();                          // B4: window reads done, sred(B) ready
    float woff2 = 0.f;
    #pragma unroll
    for (int w = 0; w < 4; ++w) if (w < wave) woff2 += sred[w];

    // ---- 5. exclusive u^2-prefix -> sp ----
    {
        float run = woff2 + iu - cu;
        if (active) {
            #pragma unroll
            for (int j = 0; j < CH; ++j) { sp[base + j] = run; run = fmaf(y[j], y[j], run); }
            if (tid == NCHUNK - 1) sp[L] = run;
        }
    }
    __syncthreads();                          // B5: u^2-prefix ready

    // ---- 6. epilogue: r = u * rsqrt(W) * (1 - epsS*rsqrt(W))  [1st-order exact] ----
    const float inv501 = 1.f / 501.f;
    if (active) {
        if (tid >= 17 && tid <= 232) {        // untruncated MV windows
            #pragma unroll
            for (int j = 0; j < CH; ++j) {
                const int i = base + j;
                const float W = fmaxf((sp[i + 251] - sp[i - 250]) * inv501, 0.f);
                const float t = frsq(W);
                y[j] = y[j] * t * fmaf(-epsS, t, 1.f);
            }
        } else {                              // clamped
            #pragma unroll
            for (int j = 0; j < CH; ++j) {
                const int i  = base + j;
                const int lo = (i > 250) ? i - 250 : 0;
                const int hi = (i + 251 < L) ? i + 251 : L;
                const float W = fmaxf((sp[hi] - sp[lo]) * inv501, 0.f);
                const float t = frsq(W);
                y[j] = y[j] * t * fmaf(-epsS, t, 1.f);
            }
        }
    }
    __syncthreads();                          // B6: all prefix reads done

    // ---- 7. bounce r through sp (chunk layout == linear) ----
    if (active) {
        #pragma unroll
        for (int j = 0; j < CH; ++j) sp[base + j] = y[j];
    }
    __syncthreads();                          // B7: result staged

    // ---- 8. coalesced store (batched: all LDS reads, then global stores) ----
    {
        const float2* sp2 = reinterpret_cast<const float2*>(sp);
        float2* rout2 = reinterpret_cast<float2*>(rout);
        float2 v[NFULL + 1];
        #pragma unroll
        for (int k = 0; k < NFULL; ++k) v[k] = sp2[k * BLK + tid];
        if (tl) v[NFULL] = sp2[NFULL * BLK + tid];
        #pragma unroll
        for (int k = 0; k < NFULL; ++k) rout2[k * BLK + tid] = v[k];
        if (tl) rout2[NFULL * BLK + tid] = v[NFULL];
    }
}

}  // namespace

extern "C" void kernel_launch(void* const* d_in, const int* in_sizes, int n_in,
                              void* d_out, int out_size, void* d_ws, size_t ws_size,
                              hipStream_t stream) {
    const float* x = (const float*)d_in[0];
    float* out = (float*)d_out;
    const int rows = in_sizes[0] / L;   // 8192
    preproc_kernel<<<rows, BLK, 0, stream>>>(x, out);
}